// Round 1
// baseline (12961.734 us; speedup 1.0000x reference)
//
#include <hip/hip_runtime.h>
#include <hip/hip_bf16.h>
#include <math.h>

// GPT-nano forward, fp32 baseline.
// Shapes: B=4 T=1024 D=768 H=12 HD=64 L=6 V=32000.
#define Dm 768
#define NH 12
#define HD 64
#define NB 4
#define NT 1024
#define NL 6
#define NV 32000
#define LEPS 1e-5f

// ---------------------------------------------------------------- embedding
__global__ __launch_bounds__(256) void embed_kernel(
    const int* __restrict__ x, const float* __restrict__ tok,
    const float* __restrict__ pos, float* __restrict__ h) {
  int row = blockIdx.x;              // b*T + t
  int t = row & (NT - 1);
  int id = x[row];
  const float4* tp = (const float4*)(tok + (size_t)id * Dm);
  const float4* pp = (const float4*)(pos + (size_t)t * Dm);
  float4* hp = (float4*)(h + (size_t)row * Dm);
  for (int i = threadIdx.x; i < Dm / 4; i += 256) {
    float4 a = tp[i], b = pp[i];
    hp[i] = make_float4(a.x + b.x, a.y + b.y, a.z + b.z, a.w + b.w);
  }
}

// ---------------------------------------------------------------- layernorm
__device__ __forceinline__ float block_sum256(float v, float* red) {
#pragma unroll
  for (int off = 32; off > 0; off >>= 1) v += __shfl_down(v, off, 64);
  __syncthreads();  // guard red[] reuse from a previous call
  if ((threadIdx.x & 63) == 0) red[threadIdx.x >> 6] = v;
  __syncthreads();
  return red[0] + red[1] + red[2] + red[3];
}

// one block (256 threads) per row of 768
__global__ __launch_bounds__(256) void ln_kernel(
    const float* __restrict__ in, const float* __restrict__ s,
    const float* __restrict__ b, float* __restrict__ out) {
  __shared__ float red[4];
  size_t row = blockIdx.x;
  const float* xr = in + row * Dm;
  float lx0 = xr[threadIdx.x];
  float lx1 = xr[threadIdx.x + 256];
  float lx2 = xr[threadIdx.x + 512];
  float mean = block_sum256(lx0 + lx1 + lx2, red) * (1.0f / Dm);
  float d0 = lx0 - mean, d1 = lx1 - mean, d2 = lx2 - mean;
  float var = block_sum256(d0 * d0 + d1 * d1 + d2 * d2, red) * (1.0f / Dm);
  float r = 1.0f / sqrtf(var + LEPS);
  float* orow = out + row * Dm;
  orow[threadIdx.x]       = d0 * r * s[threadIdx.x]       + b[threadIdx.x];
  orow[threadIdx.x + 256] = d1 * r * s[threadIdx.x + 256] + b[threadIdx.x + 256];
  orow[threadIdx.x + 512] = d2 * r * s[threadIdx.x + 512] + b[threadIdx.x + 512];
}

// ---------------------------------------------------------------- GEMM
// C[M,N] = A[M,K] @ W[N,K]^T  (+bias[N]) (relu) (+res[M,N])
// 128x128 tile, BK=16, 256 threads, 8x8 micro-tile with interleaved rows/cols
// (r = ty+16i, c = tx+16j) so LDS reads are conflict-free with pad 17.
#define BM 128
#define BN 128
#define BK 16
#define LPAD 17

template <bool BIAS, bool RELU, bool RES>
__global__ __launch_bounds__(256) void gemm_f32(
    const float* __restrict__ A, const float* __restrict__ W,
    const float* __restrict__ bias, const float* __restrict__ res,
    float* __restrict__ C, int M, int N, int K) {
  __shared__ float As[BM * LPAD];
  __shared__ float Ws[BN * LPAD];
  const int bm = blockIdx.y * BM;
  const int bn = blockIdx.x * BN;
  const int tid = threadIdx.x;
  const int ty = tid >> 4, tx = tid & 15;
  float acc[8][8];
#pragma unroll
  for (int i = 0; i < 8; i++)
#pragma unroll
    for (int j = 0; j < 8; j++) acc[i][j] = 0.0f;

  const int lrow = tid >> 1;         // 0..127
  const int lcol = (tid & 1) * 8;    // 0 or 8
  const float* Ap = A + (size_t)(bm + lrow) * K + lcol;
  const float* Wp = W + (size_t)(bn + lrow) * K + lcol;

  for (int k0 = 0; k0 < K; k0 += BK) {
    float4 a0 = *(const float4*)(Ap + k0);
    float4 a1 = *(const float4*)(Ap + k0 + 4);
    float4 w0 = *(const float4*)(Wp + k0);
    float4 w1 = *(const float4*)(Wp + k0 + 4);
    __syncthreads();  // previous tile fully consumed
    float* as = As + lrow * LPAD + lcol;
    as[0] = a0.x; as[1] = a0.y; as[2] = a0.z; as[3] = a0.w;
    as[4] = a1.x; as[5] = a1.y; as[6] = a1.z; as[7] = a1.w;
    float* wsp = Ws + lrow * LPAD + lcol;
    wsp[0] = w0.x; wsp[1] = w0.y; wsp[2] = w0.z; wsp[3] = w0.w;
    wsp[4] = w1.x; wsp[5] = w1.y; wsp[6] = w1.z; wsp[7] = w1.w;
    __syncthreads();
#pragma unroll
    for (int k = 0; k < BK; k++) {
      float av[8], wv[8];
#pragma unroll
      for (int i = 0; i < 8; i++) av[i] = As[(ty + 16 * i) * LPAD + k];
#pragma unroll
      for (int j = 0; j < 8; j++) wv[j] = Ws[(tx + 16 * j) * LPAD + k];
#pragma unroll
      for (int i = 0; i < 8; i++)
#pragma unroll
        for (int j = 0; j < 8; j++) acc[i][j] += av[i] * wv[j];
    }
  }
#pragma unroll
  for (int i = 0; i < 8; i++) {
    int r = bm + ty + 16 * i;
#pragma unroll
    for (int j = 0; j < 8; j++) {
      int c = bn + tx + 16 * j;
      float v = acc[i][j];
      if (BIAS) v += bias[c];
      if (RELU) v = fmaxf(v, 0.0f);
      if (RES) v += res[(size_t)r * N + c];
      C[(size_t)r * N + c] = v;
    }
  }
}

// ---------------------------------------------------------------- attention
// Flash-style: block = (q-tile of 64 rows, head, batch). 64x64 K/V tiles,
// online softmax in registers (m,l duplicated across the 16 row-collaborator
// lanes), P staged through LDS for the PV product.
__global__ __launch_bounds__(256) void attn_kernel(
    const float* __restrict__ qkv,   // [B*T, 3D]
    float* __restrict__ out) {       // [B*T, D]
  __shared__ float Qs[64 * 68];
  __shared__ float Ks[64 * 68];
  __shared__ float Vs[64 * 68];
  __shared__ float Ps[64 * 68];
  const int qt = blockIdx.x;   // q tile (16)
  const int hh = blockIdx.y;   // head (12)
  const int bb = blockIdx.z;   // batch (4)
  const int tid = threadIdx.x;
  const int ty = tid >> 4, tx = tid & 15;
  const int q0 = qt * 64;
  const size_t rs = 3 * Dm;
  const float* qbase = qkv + (size_t)bb * NT * rs + hh * HD;

  {  // Q tile -> LDS (4 threads/row, 16 floats each)
    int r = tid >> 2;
    int c0 = (tid & 3) * 16;
    const float* src = qbase + (size_t)(q0 + r) * rs + c0;
    float* dst = Qs + r * 68 + c0;
#pragma unroll
    for (int u = 0; u < 4; u++)
      *(float4*)(dst + 4 * u) = *(const float4*)(src + 4 * u);
  }

  float m_i[4], l_i[4], o[4][4];
#pragma unroll
  for (int i = 0; i < 4; i++) {
    m_i[i] = -1e30f;
    l_i[i] = 0.0f;
#pragma unroll
    for (int j = 0; j < 4; j++) o[i][j] = 0.0f;
  }

  for (int kt = 0; kt <= qt; kt++) {
    __syncthreads();  // prev-iter reads of Ks/Vs/Ps done; Qs ready (iter 0)
    {  // K,V tiles -> LDS
      int r = tid >> 2;
      int c0 = (tid & 3) * 16;
      const float* ksrc = qbase + (size_t)(kt * 64 + r) * rs + Dm + c0;
      const float* vsrc = ksrc + Dm;
      float* kdst = Ks + r * 68 + c0;
      float* vdst = Vs + r * 68 + c0;
#pragma unroll
      for (int u = 0; u < 4; u++) {
        *(float4*)(kdst + 4 * u) = *(const float4*)(ksrc + 4 * u);
        *(float4*)(vdst + 4 * u) = *(const float4*)(vsrc + 4 * u);
      }
    }
    __syncthreads();

    // S = (Q K^T) * scale, causal-masked
    float sv[4][4];
#pragma unroll
    for (int i = 0; i < 4; i++)
#pragma unroll
      for (int j = 0; j < 4; j++) sv[i][j] = 0.0f;
#pragma unroll 8
    for (int d = 0; d < HD; d++) {
      float qv[4], kv[4];
#pragma unroll
      for (int i = 0; i < 4; i++) qv[i] = Qs[(ty + 16 * i) * 68 + d];
#pragma unroll
      for (int j = 0; j < 4; j++) kv[j] = Ks[(tx + 16 * j) * 68 + d];
#pragma unroll
      for (int i = 0; i < 4; i++)
#pragma unroll
        for (int j = 0; j < 4; j++) sv[i][j] += qv[i] * kv[j];
    }

    const bool diag = (kt == qt);
    float pm[4];
#pragma unroll
    for (int i = 0; i < 4; i++) {
      pm[i] = -1e30f;
#pragma unroll
      for (int j = 0; j < 4; j++) {
        float v = sv[i][j] * 0.125f;  // HD^-0.5
        if (diag && (tx + 16 * j) > (ty + 16 * i)) v = -1e30f;
        sv[i][j] = v;
        pm[i] = fmaxf(pm[i], v);
      }
    }
    // row max across the 16 collaborator lanes (consecutive, same wave)
#pragma unroll
    for (int off = 8; off > 0; off >>= 1)
#pragma unroll
      for (int i = 0; i < 4; i++)
        pm[i] = fmaxf(pm[i], __shfl_xor(pm[i], off, 64));

    float corr[4], psum[4];
#pragma unroll
    for (int i = 0; i < 4; i++) {
      float mn = fmaxf(m_i[i], pm[i]);
      corr[i] = expf(m_i[i] - mn);
      m_i[i] = mn;
      psum[i] = 0.0f;
    }
#pragma unroll
    for (int i = 0; i < 4; i++)
#pragma unroll
      for (int j = 0; j < 4; j++) {
        float p = expf(sv[i][j] - m_i[i]);
        sv[i][j] = p;
        psum[i] += p;
      }
#pragma unroll
    for (int off = 8; off > 0; off >>= 1)
#pragma unroll
      for (int i = 0; i < 4; i++)
        psum[i] += __shfl_xor(psum[i], off, 64);
#pragma unroll
    for (int i = 0; i < 4; i++) l_i[i] = l_i[i] * corr[i] + psum[i];

#pragma unroll
    for (int i = 0; i < 4; i++)
#pragma unroll
      for (int j = 0; j < 4; j++) {
        Ps[(ty + 16 * i) * 68 + (tx + 16 * j)] = sv[i][j];
        o[i][j] *= corr[i];
      }
    __syncthreads();

    // O += P V
#pragma unroll 8
    for (int c = 0; c < 64; c++) {
      float pv[4], vv[4];
#pragma unroll
      for (int i = 0; i < 4; i++) pv[i] = Ps[(ty + 16 * i) * 68 + c];
#pragma unroll
      for (int j = 0; j < 4; j++) vv[j] = Vs[c * 68 + tx + 16 * j];
#pragma unroll
      for (int i = 0; i < 4; i++)
#pragma unroll
        for (int j = 0; j < 4; j++) o[i][j] += pv[i] * vv[j];
    }
  }

#pragma unroll
  for (int i = 0; i < 4; i++) {
    float inv = 1.0f / l_i[i];
    size_t orow = ((size_t)bb * NT + q0 + ty + 16 * i) * Dm + hh * HD;
#pragma unroll
    for (int j = 0; j < 4; j++) out[orow + tx + 16 * j] = o[i][j] * inv;
  }
}

// ---------------------------------------------------------------- launch
extern "C" void kernel_launch(void* const* d_in, const int* in_sizes, int n_in,
                              void* d_out, int out_size, void* d_ws,
                              size_t ws_size, hipStream_t stream) {
  const int*   x     = (const int*)d_in[0];
  const float* tok   = (const float*)d_in[1];
  const float* pos   = (const float*)d_in[2];
  const float* qkv_w = (const float*)d_in[3];
  const float* fc_w  = (const float*)d_in[4];
  const float* fc_b  = (const float*)d_in[5];
  const float* ln1_s = (const float*)d_in[6];
  const float* ln1_b = (const float*)d_in[7];
  const float* ln2_s = (const float*)d_in[8];
  const float* ln2_b = (const float*)d_in[9];
  const float* ff1_w = (const float*)d_in[10];
  const float* ff1_b = (const float*)d_in[11];
  const float* ff2_w = (const float*)d_in[12];
  const float* ff2_b = (const float*)d_in[13];
  const float* lnf_s = (const float*)d_in[14];
  const float* lnf_b = (const float*)d_in[15];
  const float* out_w = (const float*)d_in[16];
  const float* out_b = (const float*)d_in[17];
  float* logits = (float*)d_out;

  const int M = NB * NT;  // 4096 token rows
  // workspace layout (floats): h | lnbuf | qkv | att | ff   (~120 MB total)
  float* h    = (float*)d_ws;
  float* lnb  = h    + (size_t)M * Dm;
  float* qkvb = lnb  + (size_t)M * Dm;
  float* attb = qkvb + (size_t)M * 3 * Dm;
  float* ffb  = attb + (size_t)M * Dm;

  embed_kernel<<<M, 256, 0, stream>>>(x, tok, pos, h);

  for (int l = 0; l < NL; l++) {
    ln_kernel<<<M, 256, 0, stream>>>(h, ln1_s + (size_t)l * Dm,
                                     ln1_b + (size_t)l * Dm, lnb);
    gemm_f32<false, false, false>
        <<<dim3(3 * Dm / BN, M / BM), 256, 0, stream>>>(
            lnb, qkv_w + (size_t)l * 3 * Dm * Dm, nullptr, nullptr, qkvb, M,
            3 * Dm, Dm);
    attn_kernel<<<dim3(NT / 64, NH, NB), 256, 0, stream>>>(qkvb, attb);
    gemm_f32<true, false, true>
        <<<dim3(Dm / BN, M / BM), 256, 0, stream>>>(
            attb, fc_w + (size_t)l * Dm * Dm, fc_b + (size_t)l * Dm, h, h, M,
            Dm, Dm);
    ln_kernel<<<M, 256, 0, stream>>>(h, ln2_s + (size_t)l * Dm,
                                     ln2_b + (size_t)l * Dm, lnb);
    gemm_f32<true, true, false>
        <<<dim3(4 * Dm / BN, M / BM), 256, 0, stream>>>(
            lnb, ff1_w + (size_t)l * 4 * Dm * Dm, ff1_b + (size_t)l * 4 * Dm,
            nullptr, ffb, M, 4 * Dm, Dm);
    gemm_f32<true, false, true>
        <<<dim3(Dm / BN, M / BM), 256, 0, stream>>>(
            ffb, ff2_w + (size_t)l * Dm * 4 * Dm, ff2_b + (size_t)l * Dm, h, h,
            M, Dm, 4 * Dm);
  }

  ln_kernel<<<M, 256, 0, stream>>>(h, lnf_s, lnf_b, lnb);
  gemm_f32<true, false, false>
      <<<dim3(NV / BN, M / BM), 256, 0, stream>>>(lnb, out_w, out_b, nullptr,
                                                  logits, M, NV, Dm);
}

// Round 2
// 3730.235 us; speedup vs baseline: 3.4748x; 3.4748x over previous
//
#include <hip/hip_runtime.h>
#include <hip/hip_bf16.h>
#include <math.h>

// GPT-nano forward. Round 1: bf16 MFMA GEMMs (m97 structure), fp32 attention
// on bf16 inputs, fp32 residual stream.
// Shapes: B=4 T=1024 D=768 H=12 HD=64 L=6 V=32000.
#define Dm 768
#define NH 12
#define HD 64
#define NB 4
#define NT 1024
#define NL 6
#define NV 32000
#define LEPS 1e-5f

typedef __bf16 bf16x8 __attribute__((ext_vector_type(8)));
typedef float f32x4 __attribute__((ext_vector_type(4)));
typedef unsigned short ushort4v __attribute__((ext_vector_type(4)));

__device__ __forceinline__ unsigned short f2bf(float f) {
  unsigned int b = __float_as_uint(f);
  b += 0x7fff + ((b >> 16) & 1);  // RNE
  return (unsigned short)(b >> 16);
}

// ---------------------------------------------------------------- fp32->bf16
__global__ __launch_bounds__(256) void f2bf_kernel(
    const float* __restrict__ in, unsigned short* __restrict__ out, int n4) {
  int stride = gridDim.x * 256;
  for (int i = blockIdx.x * 256 + threadIdx.x; i < n4; i += stride) {
    float4 v = ((const float4*)in)[i];
    ushort4v o;
    o.x = f2bf(v.x); o.y = f2bf(v.y); o.z = f2bf(v.z); o.w = f2bf(v.w);
    ((ushort4v*)out)[i] = o;
  }
}

// ---------------------------------------------------------------- embedding
__global__ __launch_bounds__(256) void embed_kernel(
    const int* __restrict__ x, const float* __restrict__ tok,
    const float* __restrict__ pos, float* __restrict__ h) {
  int row = blockIdx.x;  // b*T + t
  int t = row & (NT - 1);
  int id = x[row];
  const float4* tp = (const float4*)(tok + (size_t)id * Dm);
  const float4* pp = (const float4*)(pos + (size_t)t * Dm);
  float4* hp = (float4*)(h + (size_t)row * Dm);
  for (int i = threadIdx.x; i < Dm / 4; i += 256) {
    float4 a = tp[i], b = pp[i];
    hp[i] = make_float4(a.x + b.x, a.y + b.y, a.z + b.z, a.w + b.w);
  }
}

// ---------------------------------------------------------------- layernorm
__device__ __forceinline__ float block_sum256(float v, float* red) {
#pragma unroll
  for (int off = 32; off > 0; off >>= 1) v += __shfl_down(v, off, 64);
  __syncthreads();
  if ((threadIdx.x & 63) == 0) red[threadIdx.x >> 6] = v;
  __syncthreads();
  return red[0] + red[1] + red[2] + red[3];
}

// one block (256 threads) per row of 768; fp32 in, bf16 out
__global__ __launch_bounds__(256) void ln_kernel(
    const float* __restrict__ in, const float* __restrict__ s,
    const float* __restrict__ b, unsigned short* __restrict__ out) {
  __shared__ float red[4];
  size_t row = blockIdx.x;
  const float* xr = in + row * Dm;
  float lx0 = xr[threadIdx.x];
  float lx1 = xr[threadIdx.x + 256];
  float lx2 = xr[threadIdx.x + 512];
  float mean = block_sum256(lx0 + lx1 + lx2, red) * (1.0f / Dm);
  float d0 = lx0 - mean, d1 = lx1 - mean, d2 = lx2 - mean;
  float var = block_sum256(d0 * d0 + d1 * d1 + d2 * d2, red) * (1.0f / Dm);
  float r = 1.0f / sqrtf(var + LEPS);
  unsigned short* orow = out + row * Dm;
  orow[threadIdx.x] = f2bf(d0 * r * s[threadIdx.x] + b[threadIdx.x]);
  orow[threadIdx.x + 256] =
      f2bf(d1 * r * s[threadIdx.x + 256] + b[threadIdx.x + 256]);
  orow[threadIdx.x + 512] =
      f2bf(d2 * r * s[threadIdx.x + 512] + b[threadIdx.x + 512]);
}

// ---------------------------------------------------------------- bf16 GEMM
// C[M,N] = A[M,K] @ W[N,K]^T (+bias) (relu) (+res). m97 structure:
// 128x128 tile, BK=32, 4 waves in 2x2, each wave 4x4 frags of 16x16x32 MFMA,
// global_load_lds width-16 staging, 2 barriers per K-step.
#define GBM 128
#define GBN 128
#define GBK 32

__device__ __forceinline__ void gload16(const unsigned short* g,
                                        unsigned short* l) {
  __builtin_amdgcn_global_load_lds(
      (const __attribute__((address_space(1))) unsigned int*)g,
      (__attribute__((address_space(3))) unsigned int*)l, 16, 0, 0);
}

// OUTBF: 1 = bf16 out, 0 = f32 out
template <int OUTBF, bool BIAS, bool RELU, bool RES>
__global__ __launch_bounds__(256) void gemm_bf16(
    const unsigned short* __restrict__ A,  // [M,K] bf16
    const unsigned short* __restrict__ W,  // [N,K] bf16
    const float* __restrict__ bias, const float* res, void* Cout, int M, int N,
    int K) {
  __shared__ __align__(16) unsigned short As[GBM * GBK];
  __shared__ __align__(16) unsigned short Ws[GBN * GBK];
  const int bm = blockIdx.y * GBM, bn = blockIdx.x * GBN;
  const int tid = threadIdx.x;
  const int l = tid & 63;
  const int w = tid >> 6;        // wave 0..3
  const int wr = (w >> 1) * 64;  // wave row offset in tile
  const int wc = (w & 1) * 64;   // wave col offset in tile
  const int lr = l & 15;         // fragment row/col lane
  const int lk = (l >> 4) * 8;   // fragment k-chunk (elements)

  f32x4 acc[4][4];
#pragma unroll
  for (int i = 0; i < 4; i++)
#pragma unroll
    for (int j = 0; j < 4; j++) acc[i][j] = (f32x4)(0.0f);

  // staging: chunk cidx = u*256+tid covers 16B; row = cidx/4, sub = cidx%4
  const int arow = tid >> 2, asub = (tid & 3) * 8;
  const unsigned short* Ap = A + (size_t)(bm + arow) * K + asub;
  const unsigned short* Ap2 = A + (size_t)(bm + 64 + arow) * K + asub;
  const unsigned short* Wp = W + (size_t)(bn + arow) * K + asub;
  const unsigned short* Wp2 = W + (size_t)(bn + 64 + arow) * K + asub;
  // LDS dest (wave-uniform): issue u of wave w -> byte base (u*4+w)*1024
  unsigned short* AsW = As + (w * 1024) / 2;
  unsigned short* WsW = Ws + (w * 1024) / 2;

  for (int k0 = 0; k0 < K; k0 += GBK) {
    __syncthreads();  // all waves done reading previous tile
    gload16(Ap + k0, AsW);
    gload16(Ap2 + k0, AsW + 2048);
    gload16(Wp + k0, WsW);
    gload16(Wp2 + k0, WsW + 2048);
    __syncthreads();  // staging complete (compiler drains vmcnt before barrier)

    bf16x8 af[4], bf[4];
#pragma unroll
    for (int i = 0; i < 4; i++)
      af[i] = *reinterpret_cast<const bf16x8*>(
          &As[(wr + i * 16 + lr) * GBK + lk]);
#pragma unroll
    for (int j = 0; j < 4; j++)
      bf[j] = *reinterpret_cast<const bf16x8*>(
          &Ws[(wc + j * 16 + lr) * GBK + lk]);
#pragma unroll
    for (int i = 0; i < 4; i++)
#pragma unroll
      for (int j = 0; j < 4; j++)
        acc[i][j] = __builtin_amdgcn_mfma_f32_16x16x32_bf16(af[i], bf[j],
                                                            acc[i][j], 0, 0, 0);
  }

  // epilogue: C/D layout col = lane&15, row = (lane>>4)*4 + reg
  const int c_l = l & 15, r_l = (l >> 4) * 4;
#pragma unroll
  for (int j = 0; j < 4; j++) {
    int col = bn + wc + j * 16 + c_l;
    float bv = BIAS ? bias[col] : 0.0f;
#pragma unroll
    for (int i = 0; i < 4; i++) {
#pragma unroll
      for (int r = 0; r < 4; r++) {
        int row = bm + wr + i * 16 + r_l + r;
        float v = acc[i][j][r] + bv;
        if (RELU) v = fmaxf(v, 0.0f);
        if (RES) v += res[(size_t)row * N + col];
        if (OUTBF)
          ((unsigned short*)Cout)[(size_t)row * N + col] = f2bf(v);
        else
          ((float*)Cout)[(size_t)row * N + col] = v;
      }
    }
  }
}

// ---------------------------------------------------------------- attention
// Flash-style fp32 compute, bf16 I/O. block = (q-tile 64, head, batch).
__device__ __forceinline__ void unpack8(const uint4 u, float* d) {
  d[0] = __uint_as_float(u.x << 16);
  d[1] = __uint_as_float(u.x & 0xffff0000u);
  d[2] = __uint_as_float(u.y << 16);
  d[3] = __uint_as_float(u.y & 0xffff0000u);
  d[4] = __uint_as_float(u.z << 16);
  d[5] = __uint_as_float(u.z & 0xffff0000u);
  d[6] = __uint_as_float(u.w << 16);
  d[7] = __uint_as_float(u.w & 0xffff0000u);
}

__device__ __forceinline__ void stage16(const unsigned short* src, float* dst) {
  uint4 u0 = *(const uint4*)src;
  uint4 u1 = *(const uint4*)(src + 8);
  float f[16];
  unpack8(u0, f);
  unpack8(u1, f + 8);
#pragma unroll
  for (int q = 0; q < 4; q++)
    *(float4*)(dst + 4 * q) =
        make_float4(f[4 * q], f[4 * q + 1], f[4 * q + 2], f[4 * q + 3]);
}

__global__ __launch_bounds__(256) void attn_kernel(
    const unsigned short* __restrict__ qkv,  // [B*T, 3D] bf16
    unsigned short* __restrict__ out) {      // [B*T, D] bf16
  __shared__ float Qs[64 * 68];
  __shared__ float Ks[64 * 68];
  __shared__ float Vs[64 * 68];
  __shared__ float Ps[64 * 68];
  const int qt = blockIdx.x, hh = blockIdx.y, bb = blockIdx.z;
  const int tid = threadIdx.x;
  const int ty = tid >> 4, tx = tid & 15;
  const int q0 = qt * 64;
  const size_t rs = 3 * Dm;
  const unsigned short* qbase = qkv + (size_t)bb * NT * rs + hh * HD;

  {  // Q tile -> LDS
    int r = tid >> 2, c0 = (tid & 3) * 16;
    stage16(qbase + (size_t)(q0 + r) * rs + c0, Qs + r * 68 + c0);
  }

  float m_i[4], l_i[4], o[4][4];
#pragma unroll
  for (int i = 0; i < 4; i++) {
    m_i[i] = -1e30f;
    l_i[i] = 0.0f;
#pragma unroll
    for (int j = 0; j < 4; j++) o[i][j] = 0.0f;
  }

  for (int kt = 0; kt <= qt; kt++) {
    __syncthreads();
    {  // K,V tiles -> LDS
      int r = tid >> 2, c0 = (tid & 3) * 16;
      const unsigned short* ksrc = qbase + (size_t)(kt * 64 + r) * rs + Dm + c0;
      stage16(ksrc, Ks + r * 68 + c0);
      stage16(ksrc + Dm, Vs + r * 68 + c0);
    }
    __syncthreads();

    float sv[4][4];
#pragma unroll
    for (int i = 0; i < 4; i++)
#pragma unroll
      for (int j = 0; j < 4; j++) sv[i][j] = 0.0f;
#pragma unroll 8
    for (int d = 0; d < HD; d++) {
      float qv[4], kv[4];
#pragma unroll
      for (int i = 0; i < 4; i++) qv[i] = Qs[(ty + 16 * i) * 68 + d];
#pragma unroll
      for (int j = 0; j < 4; j++) kv[j] = Ks[(tx + 16 * j) * 68 + d];
#pragma unroll
      for (int i = 0; i < 4; i++)
#pragma unroll
        for (int j = 0; j < 4; j++) sv[i][j] += qv[i] * kv[j];
    }

    const bool diag = (kt == qt);
    float pm[4];
#pragma unroll
    for (int i = 0; i < 4; i++) {
      pm[i] = -1e30f;
#pragma unroll
      for (int j = 0; j < 4; j++) {
        float v = sv[i][j] * 0.125f;
        if (diag && (tx + 16 * j) > (ty + 16 * i)) v = -1e30f;
        sv[i][j] = v;
        pm[i] = fmaxf(pm[i], v);
      }
    }
#pragma unroll
    for (int off = 8; off > 0; off >>= 1)
#pragma unroll
      for (int i = 0; i < 4; i++)
        pm[i] = fmaxf(pm[i], __shfl_xor(pm[i], off, 64));

    float corr[4], psum[4];
#pragma unroll
    for (int i = 0; i < 4; i++) {
      float mn = fmaxf(m_i[i], pm[i]);
      corr[i] = expf(m_i[i] - mn);
      m_i[i] = mn;
      psum[i] = 0.0f;
    }
#pragma unroll
    for (int i = 0; i < 4; i++)
#pragma unroll
      for (int j = 0; j < 4; j++) {
        float p = expf(sv[i][j] - m_i[i]);
        sv[i][j] = p;
        psum[i] += p;
      }
#pragma unroll
    for (int off = 8; off > 0; off >>= 1)
#pragma unroll
      for (int i = 0; i < 4; i++) psum[i] += __shfl_xor(psum[i], off, 64);
#pragma unroll
    for (int i = 0; i < 4; i++) l_i[i] = l_i[i] * corr[i] + psum[i];

#pragma unroll
    for (int i = 0; i < 4; i++)
#pragma unroll
      for (int j = 0; j < 4; j++) {
        Ps[(ty + 16 * i) * 68 + (tx + 16 * j)] = sv[i][j];
        o[i][j] *= corr[i];
      }
    __syncthreads();

#pragma unroll 8
    for (int c = 0; c < 64; c++) {
      float pv[4], vv[4];
#pragma unroll
      for (int i = 0; i < 4; i++) pv[i] = Ps[(ty + 16 * i) * 68 + c];
#pragma unroll
      for (int j = 0; j < 4; j++) vv[j] = Vs[c * 68 + tx + 16 * j];
#pragma unroll
      for (int i = 0; i < 4; i++)
#pragma unroll
        for (int j = 0; j < 4; j++) o[i][j] += pv[i] * vv[j];
    }
  }

#pragma unroll
  for (int i = 0; i < 4; i++) {
    float inv = 1.0f / l_i[i];
    size_t orow = ((size_t)bb * NT + q0 + ty + 16 * i) * Dm + hh * HD;
#pragma unroll
    for (int j = 0; j < 4; j++)
      out[orow + tx + 16 * j] = f2bf(o[i][j] * inv);
  }
}

// ---------------------------------------------------------------- launch
extern "C" void kernel_launch(void* const* d_in, const int* in_sizes, int n_in,
                              void* d_out, int out_size, void* d_ws,
                              size_t ws_size, hipStream_t stream) {
  const int* x = (const int*)d_in[0];
  const float* tok = (const float*)d_in[1];
  const float* pos = (const float*)d_in[2];
  const float* qkv_w = (const float*)d_in[3];
  const float* fc_w = (const float*)d_in[4];
  const float* fc_b = (const float*)d_in[5];
  const float* ln1_s = (const float*)d_in[6];
  const float* ln1_b = (const float*)d_in[7];
  const float* ln2_s = (const float*)d_in[8];
  const float* ln2_b = (const float*)d_in[9];
  const float* ff1_w = (const float*)d_in[10];
  const float* ff1_b = (const float*)d_in[11];
  const float* ff2_w = (const float*)d_in[12];
  const float* ff2_b = (const float*)d_in[13];
  const float* lnf_s = (const float*)d_in[14];
  const float* lnf_b = (const float*)d_in[15];
  const float* out_w = (const float*)d_in[16];
  const float* out_b = (const float*)d_in[17];
  float* logits = (float*)d_out;

  const int M = NB * NT;  // 4096
  // ws layout: h(f32) | lnb | qkvb | attb | ffb | bf16 weights  (~203 MB)
  float* h = (float*)d_ws;
  unsigned short* lnb = (unsigned short*)(h + (size_t)M * Dm);
  unsigned short* qkvb = lnb + (size_t)M * Dm;
  unsigned short* attb = qkvb + (size_t)M * 3 * Dm;
  unsigned short* ffb = attb + (size_t)M * Dm;
  unsigned short* wq = ffb + (size_t)M * 4 * Dm;
  const size_t nq = (size_t)NL * 3 * Dm * Dm;    // 10,616,832
  const size_t nfc = (size_t)NL * Dm * Dm;       //  3,538,944
  const size_t nf1 = (size_t)NL * 4 * Dm * Dm;   // 14,155,776
  const size_t nout = (size_t)NV * Dm;           // 24,576,000
  unsigned short* wfc = wq + nq;
  unsigned short* wf1 = wfc + nfc;
  unsigned short* wf2 = wf1 + nf1;
  unsigned short* wout = wf2 + nf1;

  // weight conversion (every call; ws is re-poisoned between calls)
  f2bf_kernel<<<2048, 256, 0, stream>>>(qkv_w, wq, (int)(nq / 4));
  f2bf_kernel<<<2048, 256, 0, stream>>>(fc_w, wfc, (int)(nfc / 4));
  f2bf_kernel<<<2048, 256, 0, stream>>>(ff1_w, wf1, (int)(nf1 / 4));
  f2bf_kernel<<<2048, 256, 0, stream>>>(ff2_w, wf2, (int)(nf1 / 4));
  f2bf_kernel<<<2048, 256, 0, stream>>>(out_w, wout, (int)(nout / 4));

  embed_kernel<<<M, 256, 0, stream>>>(x, tok, pos, h);

  for (int l = 0; l < NL; l++) {
    ln_kernel<<<M, 256, 0, stream>>>(h, ln1_s + (size_t)l * Dm,
                                     ln1_b + (size_t)l * Dm, lnb);
    gemm_bf16<1, false, false, false>
        <<<dim3(3 * Dm / GBN, M / GBM), 256, 0, stream>>>(
            lnb, wq + (size_t)l * 3 * Dm * Dm, nullptr, nullptr, qkvb, M,
            3 * Dm, Dm);
    attn_kernel<<<dim3(NT / 64, NH, NB), 256, 0, stream>>>(qkvb, attb);
    gemm_bf16<0, true, false, true>
        <<<dim3(Dm / GBN, M / GBM), 256, 0, stream>>>(
            attb, wfc + (size_t)l * Dm * Dm, fc_b + (size_t)l * Dm, h, h, M, Dm,
            Dm);
    ln_kernel<<<M, 256, 0, stream>>>(h, ln2_s + (size_t)l * Dm,
                                     ln2_b + (size_t)l * Dm, lnb);
    gemm_bf16<1, true, true, false>
        <<<dim3(4 * Dm / GBN, M / GBM), 256, 0, stream>>>(
            lnb, wf1 + (size_t)l * 4 * Dm * Dm, ff1_b + (size_t)l * 4 * Dm,
            nullptr, ffb, M, 4 * Dm, Dm);
    gemm_bf16<0, true, false, true>
        <<<dim3(Dm / GBN, M / GBM), 256, 0, stream>>>(
            ffb, wf2 + (size_t)l * Dm * 4 * Dm, ff2_b + (size_t)l * Dm, h, h, M,
            Dm, 4 * Dm);
  }

  ln_kernel<<<M, 256, 0, stream>>>(h, lnf_s, lnf_b, lnb);
  gemm_bf16<0, true, false, false>
      <<<dim3(NV / GBN, M / GBM), 256, 0, stream>>>(lnb, wout, out_b, nullptr,
                                                    logits, M, NV, Dm);
}